// Round 1
// baseline (6630.304 us; speedup 1.0000x reference)
//
#include <hip/hip_runtime.h>
#include <math.h>

#define N_NODES 50000
#define N_EDGES 800000

// ---------------------------------------------------------------------------
// GEMM: Y[N,M] = X[N,K] @ W[K,M], fp32 vector ALU (no fp32 MFMA on CDNA4).
// 64x64 tile, 256 threads, 4x4 microtile, BK=16.
// ---------------------------------------------------------------------------
__global__ __launch_bounds__(256) void gemm_tile64(
    const float* __restrict__ X, const float* __restrict__ W,
    float* __restrict__ Y, int N, int K, int M) {
  __shared__ float As[16][64];  // As[k][n]
  __shared__ float Bs[16][64];  // Bs[k][m]
  const int tile_n = blockIdx.x * 64;
  const int tile_m = blockIdx.y * 64;
  const int t = threadIdx.x;
  const int tx = t & 15, ty = t >> 4;
  float acc[4][4] = {{0.f}};
  for (int k0 = 0; k0 < K; k0 += 16) {
    {
      int n = t >> 2;
      int kk = (t & 3) << 2;
      int gn = tile_n + n;
      float4 v = make_float4(0.f, 0.f, 0.f, 0.f);
      if (gn < N) v = *(const float4*)(X + (size_t)gn * K + k0 + kk);
      As[kk + 0][n] = v.x; As[kk + 1][n] = v.y;
      As[kk + 2][n] = v.z; As[kk + 3][n] = v.w;
      int bk = t >> 4;
      int bm = (t & 15) << 2;
      float4 w = *(const float4*)(W + (size_t)(k0 + bk) * M + tile_m + bm);
      *(float4*)&Bs[bk][bm] = w;
    }
    __syncthreads();
#pragma unroll
    for (int k = 0; k < 16; ++k) {
      float4 a = *(const float4*)&As[k][ty << 2];
      float4 b = *(const float4*)&Bs[k][tx << 2];
      acc[0][0] += a.x * b.x; acc[0][1] += a.x * b.y; acc[0][2] += a.x * b.z; acc[0][3] += a.x * b.w;
      acc[1][0] += a.y * b.x; acc[1][1] += a.y * b.y; acc[1][2] += a.y * b.z; acc[1][3] += a.y * b.w;
      acc[2][0] += a.z * b.x; acc[2][1] += a.z * b.y; acc[2][2] += a.z * b.z; acc[2][3] += a.z * b.w;
      acc[3][0] += a.w * b.x; acc[3][1] += a.w * b.y; acc[3][2] += a.w * b.z; acc[3][3] += a.w * b.w;
    }
    __syncthreads();
  }
#pragma unroll
  for (int i = 0; i < 4; ++i) {
    int gn = tile_n + (ty << 2) + i;
    if (gn < N) {
      float4 o = make_float4(acc[i][0], acc[i][1], acc[i][2], acc[i][3]);
      *(float4*)(Y + (size_t)gn * M + tile_m + (tx << 2)) = o;
    }
  }
}

// ---------------------------------------------------------------------------
// el[n,h] = sum_f h[n,h,f]*al[h,f];  er likewise. One wave per node.
// ---------------------------------------------------------------------------
template <int H, int F>
__global__ __launch_bounds__(256) void elr_kernel(
    const float* __restrict__ hfeat, const float* __restrict__ al,
    const float* __restrict__ ar, float* __restrict__ el,
    float* __restrict__ er, int N) {
  int node = blockIdx.x * 4 + (threadIdx.x >> 6);
  int lane = threadIdx.x & 63;
  if (node >= N) return;
  constexpr int V = (H * F) / 64;   // floats per lane (4 for H=4, 1 for H=1)
  constexpr int G = F / V;          // lanes per head group (16 or 64)
  int base = lane * V;
  int head = base / F;
  int fo = base % F;
  float sl = 0.f, sr = 0.f;
#pragma unroll
  for (int v = 0; v < V; ++v) {
    float x = hfeat[(size_t)node * H * F + base + v];
    sl += x * al[head * F + fo + v];
    sr += x * ar[head * F + fo + v];
  }
#pragma unroll
  for (int off = G / 2; off > 0; off >>= 1) {
    sl += __shfl_xor(sl, off, G);
    sr += __shfl_xor(sr, off, G);
  }
  if ((lane % G) == 0) {
    el[node * H + head] = sl;
    er[node * H + head] = sr;
  }
}

// init m keys to INT_MIN and s to 0
__global__ void init_ms(int* __restrict__ mkey, float* __restrict__ s, int n) {
  int i = blockIdx.x * blockDim.x + threadIdx.x;
  if (i < n) { mkey[i] = (int)0x80000000; s[i] = 0.f; }
}

__device__ __forceinline__ int f2key(float f) {
  int b = __float_as_int(f);
  return b ^ ((b >> 31) & 0x7FFFFFFF);
}
__device__ __forceinline__ float key2f(int k) {
  int b = (k >= 0) ? k : (k ^ 0x7FFFFFFF);
  return __int_as_float(b);
}

// e = leaky_relu(el[src]+er[dst]); atomicMax key into m[dst]
template <int H>
__global__ __launch_bounds__(256) void edge_e_k(
    const float* __restrict__ el, const float* __restrict__ er,
    const int* __restrict__ src, const int* __restrict__ dst,
    float* __restrict__ ebuf, int* __restrict__ mkey, int E) {
  int i = blockIdx.x * blockDim.x + threadIdx.x;
  if (i >= E * H) return;
  int e_id = i / H, h = i % H;
  int sN = src[e_id], dN = dst[e_id];
  float v = el[sN * H + h] + er[dN * H + h];
  v = (v >= 0.f) ? v : 0.2f * v;
  ebuf[i] = v;
  atomicMax(&mkey[dN * H + h], f2key(v));
}

// ex = exp(e - m[dst]); s[dst] += ex
template <int H>
__global__ __launch_bounds__(256) void edge_exp_k(
    float* __restrict__ ebuf, const int* __restrict__ mkey,
    float* __restrict__ s, const int* __restrict__ dst, int E) {
  int i = blockIdx.x * blockDim.x + threadIdx.x;
  if (i >= E * H) return;
  int e_id = i / H, h = i % H;
  int dN = dst[e_id];
  float m = key2f(mkey[dN * H + h]);
  float ex = __expf(ebuf[i] - m);
  ebuf[i] = ex;
  atomicAdd(&s[dN * H + h], ex);
}

// alpha = ex / s[dst]
template <int H>
__global__ __launch_bounds__(256) void edge_alpha_k(
    float* __restrict__ ebuf, const float* __restrict__ s,
    const int* __restrict__ dst, int E) {
  int i = blockIdx.x * blockDim.x + threadIdx.x;
  if (i >= E * H) return;
  int e_id = i / H, h = i % H;
  ebuf[i] = ebuf[i] / s[dst[e_id] * H + h];
}

// out[dst] += h[src] * alpha  (vec4 per thread, atomics)
template <int H, int F>
__global__ __launch_bounds__(256) void edge_agg_k(
    const float* __restrict__ alpha, const float* __restrict__ hfeat,
    const int* __restrict__ src, const int* __restrict__ dst,
    float* __restrict__ out, int E) {
  constexpr int TPE = H * F / 4;  // threads per edge
  int i = blockIdx.x * blockDim.x + threadIdx.x;
  int e_id = i / TPE;
  if (e_id >= E) return;
  int r = i % TPE;
  int sN = src[e_id], dN = dst[e_id];
  int off = r * 4;
  int head = off / F;
  float a = alpha[e_id * H + head];
  float4 v = *(const float4*)(hfeat + (size_t)sN * H * F + off);
  float* o = out + (size_t)dN * H * F + off;
  atomicAdd(o + 0, v.x * a);
  atomicAdd(o + 1, v.y * a);
  atomicAdd(o + 2, v.z * a);
  atomicAdd(o + 3, v.w * a);
}

// f = (relu?) (f + bias)
__global__ __launch_bounds__(256) void bias_act_k(
    float* __restrict__ f, const float* __restrict__ b, int total, int HF,
    int do_relu) {
  int i = blockIdx.x * blockDim.x + threadIdx.x;
  if (i >= total) return;
  float v = f[i] + b[i % HF];
  if (do_relu) v = fmaxf(v, 0.f);
  f[i] = v;
}

// ---------------------------------------------------------------------------
template <int H>
static void run_layer(const float* X, int K, const float* W, const float* al,
                      const float* ar, const float* bias, const int* src,
                      const int* dst, float* h, float* fout, float* ebuf,
                      float* el, float* er, int* mkey, float* s, int do_relu,
                      hipStream_t stream) {
  constexpr int F = 64;
  constexpr int M = H * F;
  const int N = N_NODES, E = N_EDGES;
  hipLaunchKernelGGL(gemm_tile64, dim3((N + 63) / 64, M / 64), dim3(256), 0,
                     stream, X, W, h, N, K, M);
  hipLaunchKernelGGL((elr_kernel<H, F>), dim3((N + 3) / 4), dim3(256), 0,
                     stream, h, al, ar, el, er, N);
  hipLaunchKernelGGL(init_ms, dim3((N * H + 255) / 256), dim3(256), 0, stream,
                     mkey, s, N * H);
  hipLaunchKernelGGL((edge_e_k<H>), dim3((E * H + 255) / 256), dim3(256), 0,
                     stream, el, er, src, dst, ebuf, mkey, E);
  hipLaunchKernelGGL((edge_exp_k<H>), dim3((E * H + 255) / 256), dim3(256), 0,
                     stream, ebuf, mkey, s, dst, E);
  hipLaunchKernelGGL((edge_alpha_k<H>), dim3((E * H + 255) / 256), dim3(256),
                     0, stream, ebuf, s, dst, E);
  hipMemsetAsync(fout, 0, (size_t)N * M * sizeof(float), stream);
  constexpr int TPE = H * F / 4;
  hipLaunchKernelGGL((edge_agg_k<H, F>), dim3(((size_t)E * TPE + 255) / 256),
                     dim3(256), 0, stream, ebuf, h, src, dst, fout, E);
  hipLaunchKernelGGL(bias_act_k, dim3((N * M + 255) / 256), dim3(256), 0,
                     stream, fout, bias, N * M, M, do_relu);
}

extern "C" void kernel_launch(void* const* d_in, const int* in_sizes, int n_in,
                              void* d_out, int out_size, void* d_ws,
                              size_t ws_size, hipStream_t stream) {
  const float* feat = (const float*)d_in[0];
  const int* src = (const int*)d_in[1];
  const int* dst = (const int*)d_in[2];
  const float* W1 = (const float*)d_in[3];
  const float* al1 = (const float*)d_in[4];
  const float* ar1 = (const float*)d_in[5];
  const float* b1 = (const float*)d_in[6];
  const float* W2 = (const float*)d_in[7];
  const float* al2 = (const float*)d_in[8];
  const float* ar2 = (const float*)d_in[9];
  const float* b2 = (const float*)d_in[10];
  const float* W3 = (const float*)d_in[11];
  const float* al3 = (const float*)d_in[12];
  const float* ar3 = (const float*)d_in[13];
  const float* b3 = (const float*)d_in[14];
  float* out = (float*)d_out;

  float* h = (float*)d_ws;                          // 50000*256 f
  float* f = h + (size_t)N_NODES * 256;             // 50000*256 f
  float* ebuf = f + (size_t)N_NODES * 256;          // 800000*4 f
  float* el = ebuf + (size_t)N_EDGES * 4;           // 50000*4 f
  float* er = el + (size_t)N_NODES * 4;             // 50000*4 f
  int* mkey = (int*)(er + (size_t)N_NODES * 4);     // 50000*4 i
  float* s = (float*)(mkey + (size_t)N_NODES * 4);  // 50000*4 f

  // Layer 1: feat[50000,128] -> f[50000,256], relu
  run_layer<4>(feat, 128, W1, al1, ar1, b1, src, dst, h, f, ebuf, el, er, mkey,
               s, 1, stream);
  // Layer 2: f -> h2 (into h buffer), agg back into f... need distinct out.
  // GEMM reads f, writes h (h1 dead). Aggregation reads h, writes over f
  // (f1 dead after GEMM2). Same ping-pong as layer 1.
  run_layer<4>(f, 256, W2, al2, ar2, b2, src, dst, h, f, ebuf, el, er, mkey, s,
               1, stream);
  // Layer 3: f -> h3 (h buffer, only 50000*64 used), agg into d_out, +b3,
  // no relu; mean over 1 head is identity.
  hipMemsetAsync(out, 0, (size_t)N_NODES * 64 * sizeof(float), stream);
  {
    constexpr int H = 1, F = 64, M = 64;
    const int N = N_NODES, E = N_EDGES;
    hipLaunchKernelGGL(gemm_tile64, dim3((N + 63) / 64, 1), dim3(256), 0,
                       stream, f, W3, h, N, 256, M);
    hipLaunchKernelGGL((elr_kernel<H, F>), dim3((N + 3) / 4), dim3(256), 0,
                       stream, h, al3, ar3, el, er, N);
    hipLaunchKernelGGL(init_ms, dim3((N * H + 255) / 256), dim3(256), 0,
                       stream, mkey, s, N * H);
    hipLaunchKernelGGL((edge_e_k<H>), dim3((E * H + 255) / 256), dim3(256), 0,
                       stream, el, er, src, dst, ebuf, mkey, E);
    hipLaunchKernelGGL((edge_exp_k<H>), dim3((E * H + 255) / 256), dim3(256),
                       0, stream, ebuf, mkey, s, dst, E);
    hipLaunchKernelGGL((edge_alpha_k<H>), dim3((E * H + 255) / 256), dim3(256),
                       0, stream, ebuf, s, dst, E);
    constexpr int TPE = H * F / 4;
    hipLaunchKernelGGL((edge_agg_k<H, F>), dim3(((size_t)E * TPE + 255) / 256),
                       dim3(256), 0, stream, ebuf, h, src, dst, out, E);
    hipLaunchKernelGGL(bias_act_k, dim3((N * M + 255) / 256), dim3(256), 0,
                       stream, out, b3, N * M, M, 0);
  }
}

// Round 2
// 807.379 us; speedup vs baseline: 8.2121x; 8.2121x over previous
//
#include <hip/hip_runtime.h>
#include <math.h>

#define N_NODES 50000
#define N_EDGES 800000

// ---------------------------------------------------------------------------
// GEMM: Y[N,M] = X[N,K] @ W[K,M], fp32 vector ALU (no fp32 MFMA on CDNA4).
// 64x64 tile, 256 threads, 4x4 microtile, BK=16.
// ---------------------------------------------------------------------------
__global__ __launch_bounds__(256) void gemm_tile64(
    const float* __restrict__ X, const float* __restrict__ W,
    float* __restrict__ Y, int N, int K, int M) {
  __shared__ float As[16][64];  // As[k][n]
  __shared__ float Bs[16][64];  // Bs[k][m]
  const int tile_n = blockIdx.x * 64;
  const int tile_m = blockIdx.y * 64;
  const int t = threadIdx.x;
  const int tx = t & 15, ty = t >> 4;
  float acc[4][4] = {{0.f}};
  for (int k0 = 0; k0 < K; k0 += 16) {
    {
      int n = t >> 2;
      int kk = (t & 3) << 2;
      int gn = tile_n + n;
      float4 v = make_float4(0.f, 0.f, 0.f, 0.f);
      if (gn < N) v = *(const float4*)(X + (size_t)gn * K + k0 + kk);
      As[kk + 0][n] = v.x; As[kk + 1][n] = v.y;
      As[kk + 2][n] = v.z; As[kk + 3][n] = v.w;
      int bk = t >> 4;
      int bm = (t & 15) << 2;
      float4 w = *(const float4*)(W + (size_t)(k0 + bk) * M + tile_m + bm);
      *(float4*)&Bs[bk][bm] = w;
    }
    __syncthreads();
#pragma unroll
    for (int k = 0; k < 16; ++k) {
      float4 a = *(const float4*)&As[k][ty << 2];
      float4 b = *(const float4*)&Bs[k][tx << 2];
      acc[0][0] += a.x * b.x; acc[0][1] += a.x * b.y; acc[0][2] += a.x * b.z; acc[0][3] += a.x * b.w;
      acc[1][0] += a.y * b.x; acc[1][1] += a.y * b.y; acc[1][2] += a.y * b.z; acc[1][3] += a.y * b.w;
      acc[2][0] += a.z * b.x; acc[2][1] += a.z * b.y; acc[2][2] += a.z * b.z; acc[2][3] += a.z * b.w;
      acc[3][0] += a.w * b.x; acc[3][1] += a.w * b.y; acc[3][2] += a.w * b.z; acc[3][3] += a.w * b.w;
    }
    __syncthreads();
  }
#pragma unroll
  for (int i = 0; i < 4; ++i) {
    int gn = tile_n + (ty << 2) + i;
    if (gn < N) {
      float4 o = make_float4(acc[i][0], acc[i][1], acc[i][2], acc[i][3]);
      *(float4*)(Y + (size_t)gn * M + tile_m + (tx << 2)) = o;
    }
  }
}

// ---------------------------------------------------------------------------
// el[n,h] = sum_f h[n,h,f]*al[h,f];  er likewise. One wave per node.
// ---------------------------------------------------------------------------
template <int H, int F>
__global__ __launch_bounds__(256) void elr_kernel(
    const float* __restrict__ hfeat, const float* __restrict__ al,
    const float* __restrict__ ar, float* __restrict__ el,
    float* __restrict__ er, int N) {
  int node = blockIdx.x * 4 + (threadIdx.x >> 6);
  int lane = threadIdx.x & 63;
  if (node >= N) return;
  constexpr int V = (H * F) / 64;   // floats per lane
  constexpr int G = F / V;          // lanes per head group
  int base = lane * V;
  int head = base / F;
  int fo = base % F;
  float sl = 0.f, sr = 0.f;
#pragma unroll
  for (int v = 0; v < V; ++v) {
    float x = hfeat[(size_t)node * H * F + base + v];
    sl += x * al[head * F + fo + v];
    sr += x * ar[head * F + fo + v];
  }
#pragma unroll
  for (int off = G / 2; off > 0; off >>= 1) {
    sl += __shfl_xor(sl, off, G);
    sr += __shfl_xor(sr, off, G);
  }
  if ((lane % G) == 0) {
    el[node * H + head] = sl;
    er[node * H + head] = sr;
  }
}

// ---------------------------------------------------------------------------
// CSR build: degree histogram -> exclusive scan -> scatter src ids
// ---------------------------------------------------------------------------
__global__ __launch_bounds__(256) void count_deg_k(
    const int* __restrict__ dst, int* __restrict__ deg, int E) {
  int e = blockIdx.x * blockDim.x + threadIdx.x;
  if (e < E) atomicAdd(&deg[dst[e]], 1);
}

// single-block exclusive scan: rowptr[0]=0, rowptr[i+1]=sum(deg[0..i])
__global__ __launch_bounds__(1024) void exscan_k(
    const int* __restrict__ deg, int* __restrict__ rowptr, int n) {
  __shared__ int wsum[16];
  __shared__ int carry_s;
  int lane = threadIdx.x & 63;
  int wid = threadIdx.x >> 6;
  if (threadIdx.x == 0) carry_s = 0;
  __syncthreads();
  for (int base = 0; base < n; base += 1024) {
    int i = base + threadIdx.x;
    int v = (i < n) ? deg[i] : 0;
    int x = v;
#pragma unroll
    for (int off = 1; off < 64; off <<= 1) {
      int t = __shfl_up(x, off);
      if (lane >= off) x += t;
    }
    if (lane == 63) wsum[wid] = x;
    __syncthreads();
    if (wid == 0) {
      int ws = (lane < 16) ? wsum[lane] : 0;
      int y = ws;
#pragma unroll
      for (int off = 1; off < 16; off <<= 1) {
        int t = __shfl_up(y, off);
        if (lane >= off) y += t;
      }
      if (lane < 16) wsum[lane] = y - ws;  // exclusive wave prefix
    }
    __syncthreads();
    int carry = carry_s;
    if (i < n) rowptr[i + 1] = carry + wsum[wid] + x;
    __syncthreads();
    if (threadIdx.x == 1023) carry_s = carry + wsum[15] + x;
    __syncthreads();
  }
  if (threadIdx.x == 0) rowptr[0] = 0;
}

__global__ __launch_bounds__(256) void scatter_k(
    const int* __restrict__ src, const int* __restrict__ dst,
    int* __restrict__ cursor, int* __restrict__ src_sorted, int E) {
  int e = blockIdx.x * blockDim.x + threadIdx.x;
  if (e < E) {
    int p = atomicAdd(&cursor[dst[e]], 1);
    src_sorted[p] = src[e];
  }
}

// ---------------------------------------------------------------------------
// Per-dst-node fused softmax + aggregation, H=4, F=64. One wave per node.
// Pass 1: lane = slot*4 + head (16 edge-slots x 4 heads) -> m[h], s[h].
// Pass 2: lane = feature chunk (float4), head = lane>>4; recompute alpha,
//         accumulate 1KB gather of h[src]; single store of out row + bias.
// ---------------------------------------------------------------------------
template <int RELU>
__global__ __launch_bounds__(256) void node_agg4_k(
    const float* __restrict__ hfeat, const float* __restrict__ el,
    const float* __restrict__ er, const int* __restrict__ rowptr,
    const int* __restrict__ src_sorted, const float* __restrict__ bias,
    float* __restrict__ out, int N) {
  int node = blockIdx.x * 4 + (threadIdx.x >> 6);
  int lane = threadIdx.x & 63;
  if (node >= N) return;
  int start = rowptr[node], end = rowptr[node + 1];
  int head1 = lane & 3;
  int slot = lane >> 2;
  float er_v = er[node * 4 + head1];
  float m = -1e30f;
  for (int p = start + slot; p < end; p += 16) {
    int s = src_sorted[p];
    float v = el[s * 4 + head1] + er_v;
    v = (v >= 0.f) ? v : 0.2f * v;
    m = fmaxf(m, v);
  }
#pragma unroll
  for (int off = 4; off < 64; off <<= 1) m = fmaxf(m, __shfl_xor(m, off));
  float ssum = 0.f;
  for (int p = start + slot; p < end; p += 16) {
    int s = src_sorted[p];
    float v = el[s * 4 + head1] + er_v;
    v = (v >= 0.f) ? v : 0.2f * v;
    ssum += __expf(v - m);
  }
#pragma unroll
  for (int off = 4; off < 64; off <<= 1) ssum += __shfl_xor(ssum, off);
  // pass 2
  int hf = lane >> 4;  // head for this feature chunk (lane hf holds head hf)
  float m_f = __shfl(m, hf);
  float s_f = __shfl(ssum, hf);
  float er_f = __shfl(er_v, hf);
  float inv_s = (end > start) ? 1.f / s_f : 0.f;
  float4 acc = make_float4(0.f, 0.f, 0.f, 0.f);
  for (int p = start; p < end; ++p) {
    int s = src_sorted[p];
    float v = el[s * 4 + hf] + er_f;
    v = (v >= 0.f) ? v : 0.2f * v;
    float a = __expf(v - m_f) * inv_s;
    float4 hv = *(const float4*)(hfeat + (size_t)s * 256 + lane * 4);
    acc.x += hv.x * a; acc.y += hv.y * a;
    acc.z += hv.z * a; acc.w += hv.w * a;
  }
  float4 b = *(const float4*)(bias + lane * 4);
  acc.x += b.x; acc.y += b.y; acc.z += b.z; acc.w += b.w;
  if (RELU) {
    acc.x = fmaxf(acc.x, 0.f); acc.y = fmaxf(acc.y, 0.f);
    acc.z = fmaxf(acc.z, 0.f); acc.w = fmaxf(acc.w, 0.f);
  }
  *(float4*)(out + (size_t)node * 256 + lane * 4) = acc;
}

// H=1, F=64 variant: one wave per node, lane = feature (and edge slot).
__global__ __launch_bounds__(256) void node_agg1_k(
    const float* __restrict__ hfeat, const float* __restrict__ el,
    const float* __restrict__ er, const int* __restrict__ rowptr,
    const int* __restrict__ src_sorted, const float* __restrict__ bias,
    float* __restrict__ out, int N) {
  int node = blockIdx.x * 4 + (threadIdx.x >> 6);
  int lane = threadIdx.x & 63;
  if (node >= N) return;
  int start = rowptr[node], end = rowptr[node + 1];
  float er_v = er[node];
  float m = -1e30f;
  for (int p = start + lane; p < end; p += 64) {
    float v = el[src_sorted[p]] + er_v;
    v = (v >= 0.f) ? v : 0.2f * v;
    m = fmaxf(m, v);
  }
#pragma unroll
  for (int off = 1; off < 64; off <<= 1) m = fmaxf(m, __shfl_xor(m, off));
  float ssum = 0.f;
  for (int p = start + lane; p < end; p += 64) {
    float v = el[src_sorted[p]] + er_v;
    v = (v >= 0.f) ? v : 0.2f * v;
    ssum += __expf(v - m);
  }
#pragma unroll
  for (int off = 1; off < 64; off <<= 1) ssum += __shfl_xor(ssum, off);
  float inv_s = (end > start) ? 1.f / ssum : 0.f;
  float acc = 0.f;
  for (int p = start; p < end; ++p) {
    int s = src_sorted[p];
    float v = el[s] + er_v;
    v = (v >= 0.f) ? v : 0.2f * v;
    float a = __expf(v - m) * inv_s;
    acc += hfeat[(size_t)s * 64 + lane] * a;
  }
  out[(size_t)node * 64 + lane] = acc + bias[lane];
}

// ---------------------------------------------------------------------------
extern "C" void kernel_launch(void* const* d_in, const int* in_sizes, int n_in,
                              void* d_out, int out_size, void* d_ws,
                              size_t ws_size, hipStream_t stream) {
  const float* feat = (const float*)d_in[0];
  const int* src = (const int*)d_in[1];
  const int* dst = (const int*)d_in[2];
  const float* W1 = (const float*)d_in[3];
  const float* al1 = (const float*)d_in[4];
  const float* ar1 = (const float*)d_in[5];
  const float* b1 = (const float*)d_in[6];
  const float* W2 = (const float*)d_in[7];
  const float* al2 = (const float*)d_in[8];
  const float* ar2 = (const float*)d_in[9];
  const float* b2 = (const float*)d_in[10];
  const float* W3 = (const float*)d_in[11];
  const float* al3 = (const float*)d_in[12];
  const float* ar3 = (const float*)d_in[13];
  const float* b3 = (const float*)d_in[14];
  float* out = (float*)d_out;

  float* h = (float*)d_ws;                           // 50000*256 f
  float* f = h + (size_t)N_NODES * 256;              // 50000*256 f
  float* el = f + (size_t)N_NODES * 256;             // 50000*4
  float* er = el + (size_t)N_NODES * 4;              // 50000*4
  int* rowptr = (int*)(er + (size_t)N_NODES * 4);    // 50001
  int* deg = rowptr + (N_NODES + 1);                 // 50000 (also cursor)
  int* src_sorted = deg + N_NODES;                   // 800000

  const int N = N_NODES, E = N_EDGES;

  // ---- CSR build (dst-sorted src ids) ----
  hipMemsetAsync(deg, 0, (size_t)N * sizeof(int), stream);
  hipLaunchKernelGGL(count_deg_k, dim3((E + 255) / 256), dim3(256), 0, stream,
                     dst, deg, E);
  hipLaunchKernelGGL(exscan_k, dim3(1), dim3(1024), 0, stream, deg, rowptr, N);
  hipMemcpyAsync(deg, rowptr, (size_t)N * sizeof(int),
                 hipMemcpyDeviceToDevice, stream);  // cursor = rowptr
  hipLaunchKernelGGL(scatter_k, dim3((E + 255) / 256), dim3(256), 0, stream,
                     src, dst, deg, src_sorted, E);

  // ---- Layer 1: feat[N,128] -> f[N,256], relu ----
  hipLaunchKernelGGL(gemm_tile64, dim3((N + 63) / 64, 4), dim3(256), 0, stream,
                     feat, W1, h, N, 128, 256);
  hipLaunchKernelGGL((elr_kernel<4, 64>), dim3((N + 3) / 4), dim3(256), 0,
                     stream, h, al1, ar1, el, er, N);
  hipLaunchKernelGGL((node_agg4_k<1>), dim3((N + 3) / 4), dim3(256), 0, stream,
                     h, el, er, rowptr, src_sorted, b1, f, N);

  // ---- Layer 2: f[N,256] -> f[N,256], relu (h as temp) ----
  hipLaunchKernelGGL(gemm_tile64, dim3((N + 63) / 64, 4), dim3(256), 0, stream,
                     f, W2, h, N, 256, 256);
  hipLaunchKernelGGL((elr_kernel<4, 64>), dim3((N + 3) / 4), dim3(256), 0,
                     stream, h, al2, ar2, el, er, N);
  hipLaunchKernelGGL((node_agg4_k<1>), dim3((N + 3) / 4), dim3(256), 0, stream,
                     h, el, er, rowptr, src_sorted, b2, f, N);

  // ---- Layer 3: f[N,256] -> out[N,64], no relu, mean over 1 head = id ----
  hipLaunchKernelGGL(gemm_tile64, dim3((N + 63) / 64, 1), dim3(256), 0, stream,
                     f, W3, h, N, 256, 64);
  hipLaunchKernelGGL((elr_kernel<1, 64>), dim3((N + 3) / 4), dim3(256), 0,
                     stream, h, al3, ar3, el, er, N);
  hipLaunchKernelGGL(node_agg1_k, dim3((N + 3) / 4), dim3(256), 0, stream, h,
                     el, er, rowptr, src_sorted, b3, out, N);
}

// Round 3
// 644.136 us; speedup vs baseline: 10.2933x; 1.2534x over previous
//
#include <hip/hip_runtime.h>
#include <math.h>

#define N_NODES 50000
#define N_EDGES 800000

typedef short bf8 __attribute__((ext_vector_type(8)));   // 8 bf16 (A/B frag)
typedef float f4x __attribute__((ext_vector_type(4)));   // C/D frag

__device__ __forceinline__ unsigned short f2bf(float x) {
  unsigned u = __float_as_uint(x);
  unsigned r = (u + 0x7fff + ((u >> 16) & 1)) >> 16;  // RNE
  return (unsigned short)r;
}
__device__ __forceinline__ float bf2f(unsigned short b) {
  return __uint_as_float(((unsigned)b) << 16);
}
__device__ __forceinline__ unsigned pack2(float lo, float hi) {
  return (unsigned)f2bf(lo) | ((unsigned)f2bf(hi) << 16);
}

// ---------------------------------------------------------------------------
// MFMA GEMM: Yb_bf16[N,M] = bf16(X[N,K] fp32) @ bf16(W[K,M] fp32).
// BM=128, BN=64, BK=32; 256 threads = 4 waves; per wave 2x4 tiles of 16x16.
// A frag: lane holds A[m=lane&15][k=quad*8+j]; B frag: B[k=quad*8+j][n=lane&15]
// D: col=lane&15, row=quad*4+reg  (m89-verified layouts).
// ---------------------------------------------------------------------------
__global__ __launch_bounds__(256) void gemm_mfma_k(
    const float* __restrict__ X, const float* __restrict__ W,
    unsigned short* __restrict__ Yb, int N, int K, int M) {
  __shared__ unsigned short As[128][40];  // [m][k], +8 pad
  __shared__ unsigned short Bs[64][40];   // [n][k], +8 pad
  const int tile_n = blockIdx.x * 128;
  const int cb = blockIdx.y * 64;
  const int t = threadIdx.x;
  const int wave = t >> 6, lane = t & 63;
  const int quad = lane >> 4, l16 = lane & 15;

  f4x acc[2][4];
#pragma unroll
  for (int i = 0; i < 2; ++i)
#pragma unroll
    for (int j = 0; j < 4; ++j) acc[i][j] = (f4x){0.f, 0.f, 0.f, 0.f};

  const int ar = t >> 1;              // A stage row
  const int ac0 = (t & 1) * 16;       // A stage col base (k within tile)
  const int bn = t & 63;              // B stage col (n)
  const int bkq = t >> 6;             // B stage k-quad

  for (int k0 = 0; k0 < K; k0 += 32) {
    // --- stage A tile: 128 x 32 fp32 -> bf16 ---
    {
      int gr = tile_n + ar;
      uint4 u0, u1;
      if (gr < N) {
        const float* s = X + (size_t)gr * K + k0 + ac0;
        float4 a = *(const float4*)(s + 0);
        float4 b = *(const float4*)(s + 4);
        float4 c = *(const float4*)(s + 8);
        float4 d = *(const float4*)(s + 12);
        u0 = make_uint4(pack2(a.x, a.y), pack2(a.z, a.w),
                        pack2(b.x, b.y), pack2(b.z, b.w));
        u1 = make_uint4(pack2(c.x, c.y), pack2(c.z, c.w),
                        pack2(d.x, d.y), pack2(d.z, d.w));
      } else {
        u0 = make_uint4(0, 0, 0, 0);
        u1 = make_uint4(0, 0, 0, 0);
      }
      *(uint4*)&As[ar][ac0] = u0;
      *(uint4*)&As[ar][ac0 + 8] = u1;
    }
    // --- stage B tile: 32 x 64 fp32, transposed -> Bs[n][k] bf16 ---
    {
      const float* s = W + (size_t)(k0 + bkq * 8) * M + cb + bn;
      float w0 = s[0 * M], w1 = s[1 * M], w2 = s[2 * M], w3 = s[3 * M];
      float w4 = s[4 * M], w5 = s[5 * M], w6 = s[6 * M], w7 = s[7 * M];
      uint4 u = make_uint4(pack2(w0, w1), pack2(w2, w3), pack2(w4, w5),
                           pack2(w6, w7));
      *(uint4*)&Bs[bn][bkq * 8] = u;
    }
    __syncthreads();
    bf8 afrag[2], bfrag[4];
#pragma unroll
    for (int rt = 0; rt < 2; ++rt)
      afrag[rt] = *(const bf8*)&As[wave * 32 + rt * 16 + l16][quad * 8];
#pragma unroll
    for (int ct = 0; ct < 4; ++ct)
      bfrag[ct] = *(const bf8*)&Bs[ct * 16 + l16][quad * 8];
#pragma unroll
    for (int rt = 0; rt < 2; ++rt)
#pragma unroll
      for (int ct = 0; ct < 4; ++ct)
        acc[rt][ct] = __builtin_amdgcn_mfma_f32_16x16x32_bf16(
            afrag[rt], bfrag[ct], acc[rt][ct], 0, 0, 0);
    __syncthreads();
  }
  // --- epilogue: store bf16 ---
#pragma unroll
  for (int rt = 0; rt < 2; ++rt) {
#pragma unroll
    for (int r = 0; r < 4; ++r) {
      int row = tile_n + wave * 32 + rt * 16 + quad * 4 + r;
      if (row < N) {
#pragma unroll
        for (int ct = 0; ct < 4; ++ct)
          Yb[(size_t)row * M + cb + ct * 16 + l16] = f2bf(acc[rt][ct][r]);
      }
    }
  }
}

// ---------------------------------------------------------------------------
// el[n,h] = sum_f h[n,h,f]*al[h,f];  er likewise. One wave per node. bf16 h.
// ---------------------------------------------------------------------------
template <int H, int F>
__global__ __launch_bounds__(256) void elr_kernel(
    const unsigned short* __restrict__ hb, const float* __restrict__ al,
    const float* __restrict__ ar, float* __restrict__ el,
    float* __restrict__ er, int N) {
  int node = blockIdx.x * 4 + (threadIdx.x >> 6);
  int lane = threadIdx.x & 63;
  if (node >= N) return;
  constexpr int V = (H * F) / 64;  // bf16 per lane (4 for H=4, 1 for H=1)
  constexpr int G = F / V;         // lanes per head group
  int base = lane * V;
  int head = base / F;
  int fo = base % F;
  float sl = 0.f, sr = 0.f;
  if (V == 4) {
    ushort4 hv = *(const ushort4*)(hb + (size_t)node * H * F + base);
    float x0 = bf2f(hv.x), x1 = bf2f(hv.y), x2 = bf2f(hv.z), x3 = bf2f(hv.w);
    sl = x0 * al[head * F + fo] + x1 * al[head * F + fo + 1] +
         x2 * al[head * F + fo + 2] + x3 * al[head * F + fo + 3];
    sr = x0 * ar[head * F + fo] + x1 * ar[head * F + fo + 1] +
         x2 * ar[head * F + fo + 2] + x3 * ar[head * F + fo + 3];
  } else {
    float x = bf2f(hb[(size_t)node * H * F + base]);
    sl = x * al[head * F + fo];
    sr = x * ar[head * F + fo];
  }
#pragma unroll
  for (int off = G / 2; off > 0; off >>= 1) {
    sl += __shfl_xor(sl, off, G);
    sr += __shfl_xor(sr, off, G);
  }
  if ((lane % G) == 0) {
    el[node * H + head] = sl;
    er[node * H + head] = sr;
  }
}

// ---------------------------------------------------------------------------
// CSR build: degree histogram -> exclusive scan -> scatter src ids
// ---------------------------------------------------------------------------
__global__ __launch_bounds__(256) void count_deg_k(
    const int* __restrict__ dst, int* __restrict__ deg, int E) {
  int e = blockIdx.x * blockDim.x + threadIdx.x;
  if (e < E) atomicAdd(&deg[dst[e]], 1);
}

__global__ __launch_bounds__(1024) void exscan_k(
    const int* __restrict__ deg, int* __restrict__ rowptr, int n) {
  __shared__ int wsum[16];
  __shared__ int carry_s;
  int lane = threadIdx.x & 63;
  int wid = threadIdx.x >> 6;
  if (threadIdx.x == 0) carry_s = 0;
  __syncthreads();
  for (int base = 0; base < n; base += 1024) {
    int i = base + threadIdx.x;
    int v = (i < n) ? deg[i] : 0;
    int x = v;
#pragma unroll
    for (int off = 1; off < 64; off <<= 1) {
      int t = __shfl_up(x, off);
      if (lane >= off) x += t;
    }
    if (lane == 63) wsum[wid] = x;
    __syncthreads();
    if (wid == 0) {
      int ws = (lane < 16) ? wsum[lane] : 0;
      int y = ws;
#pragma unroll
      for (int off = 1; off < 16; off <<= 1) {
        int t = __shfl_up(y, off);
        if (lane >= off) y += t;
      }
      if (lane < 16) wsum[lane] = y - ws;
    }
    __syncthreads();
    int carry = carry_s;
    if (i < n) rowptr[i + 1] = carry + wsum[wid] + x;
    __syncthreads();
    if (threadIdx.x == 1023) carry_s = carry + wsum[15] + x;
    __syncthreads();
  }
  if (threadIdx.x == 0) rowptr[0] = 0;
}

__global__ __launch_bounds__(256) void scatter_k(
    const int* __restrict__ src, const int* __restrict__ dst,
    int* __restrict__ cursor, int* __restrict__ src_sorted, int E) {
  int e = blockIdx.x * blockDim.x + threadIdx.x;
  if (e < E) {
    int p = atomicAdd(&cursor[dst[e]], 1);
    src_sorted[p] = src[e];
  }
}

// ---------------------------------------------------------------------------
// Per-dst fused softmax + aggregation, H=4, F=64, bf16 h. One wave per node.
// ---------------------------------------------------------------------------
template <int RELU>
__global__ __launch_bounds__(256) void node_agg4_k(
    const unsigned short* __restrict__ hb, const float* __restrict__ el,
    const float* __restrict__ er, const int* __restrict__ rowptr,
    const int* __restrict__ src_sorted, const float* __restrict__ bias,
    float* __restrict__ out, int N) {
  int node = blockIdx.x * 4 + (threadIdx.x >> 6);
  int lane = threadIdx.x & 63;
  if (node >= N) return;
  int start = rowptr[node], end = rowptr[node + 1];
  int head1 = lane & 3;
  int slot = lane >> 2;
  float er_v = er[node * 4 + head1];
  float m = -1e30f;
  for (int p = start + slot; p < end; p += 16) {
    int s = src_sorted[p];
    float v = el[s * 4 + head1] + er_v;
    v = (v >= 0.f) ? v : 0.2f * v;
    m = fmaxf(m, v);
  }
#pragma unroll
  for (int off = 4; off < 64; off <<= 1) m = fmaxf(m, __shfl_xor(m, off));
  float ssum = 0.f;
  for (int p = start + slot; p < end; p += 16) {
    int s = src_sorted[p];
    float v = el[s * 4 + head1] + er_v;
    v = (v >= 0.f) ? v : 0.2f * v;
    ssum += __expf(v - m);
  }
#pragma unroll
  for (int off = 4; off < 64; off <<= 1) ssum += __shfl_xor(ssum, off);
  // pass 2: lane = feature chunk of 4; head = lane>>4
  int hf = lane >> 4;
  float m_f = __shfl(m, hf);
  float s_f = __shfl(ssum, hf);
  float er_f = __shfl(er_v, hf);
  float inv_s = (end > start) ? 1.f / s_f : 0.f;
  float4 acc = make_float4(0.f, 0.f, 0.f, 0.f);
  for (int p = start; p < end; ++p) {
    int s = src_sorted[p];
    float v = el[s * 4 + hf] + er_f;
    v = (v >= 0.f) ? v : 0.2f * v;
    float a = __expf(v - m_f) * inv_s;
    ushort4 hv = *(const ushort4*)(hb + (size_t)s * 256 + (lane << 2));
    acc.x += bf2f(hv.x) * a;
    acc.y += bf2f(hv.y) * a;
    acc.z += bf2f(hv.z) * a;
    acc.w += bf2f(hv.w) * a;
  }
  const float4 b = *(const float4*)(bias + (lane << 2));
  acc.x += b.x; acc.y += b.y; acc.z += b.z; acc.w += b.w;
  if (RELU) {
    acc.x = fmaxf(acc.x, 0.f); acc.y = fmaxf(acc.y, 0.f);
    acc.z = fmaxf(acc.z, 0.f); acc.w = fmaxf(acc.w, 0.f);
  }
  *(float4*)(out + (size_t)node * 256 + (lane << 2)) = acc;
}

// H=1, F=64 variant
__global__ __launch_bounds__(256) void node_agg1_k(
    const unsigned short* __restrict__ hb, const float* __restrict__ el,
    const float* __restrict__ er, const int* __restrict__ rowptr,
    const int* __restrict__ src_sorted, const float* __restrict__ bias,
    float* __restrict__ out, int N) {
  int node = blockIdx.x * 4 + (threadIdx.x >> 6);
  int lane = threadIdx.x & 63;
  if (node >= N) return;
  int start = rowptr[node], end = rowptr[node + 1];
  float er_v = er[node];
  float m = -1e30f;
  for (int p = start + lane; p < end; p += 64) {
    float v = el[src_sorted[p]] + er_v;
    v = (v >= 0.f) ? v : 0.2f * v;
    m = fmaxf(m, v);
  }
#pragma unroll
  for (int off = 1; off < 64; off <<= 1) m = fmaxf(m, __shfl_xor(m, off));
  float ssum = 0.f;
  for (int p = start + lane; p < end; p += 64) {
    float v = el[src_sorted[p]] + er_v;
    v = (v >= 0.f) ? v : 0.2f * v;
    ssum += __expf(v - m);
  }
#pragma unroll
  for (int off = 1; off < 64; off <<= 1) ssum += __shfl_xor(ssum, off);
  float inv_s = (end > start) ? 1.f / ssum : 0.f;
  float acc = 0.f;
  for (int p = start; p < end; ++p) {
    int s = src_sorted[p];
    float v = el[s] + er_v;
    v = (v >= 0.f) ? v : 0.2f * v;
    float a = __expf(v - m) * inv_s;
    acc += bf2f(hb[(size_t)s * 64 + lane]) * a;
  }
  out[(size_t)node * 64 + lane] = acc + bias[lane];
}

// ---------------------------------------------------------------------------
extern "C" void kernel_launch(void* const* d_in, const int* in_sizes, int n_in,
                              void* d_out, int out_size, void* d_ws,
                              size_t ws_size, hipStream_t stream) {
  const float* feat = (const float*)d_in[0];
  const int* src = (const int*)d_in[1];
  const int* dst = (const int*)d_in[2];
  const float* W1 = (const float*)d_in[3];
  const float* al1 = (const float*)d_in[4];
  const float* ar1 = (const float*)d_in[5];
  const float* b1 = (const float*)d_in[6];
  const float* W2 = (const float*)d_in[7];
  const float* al2 = (const float*)d_in[8];
  const float* ar2 = (const float*)d_in[9];
  const float* b2 = (const float*)d_in[10];
  const float* W3 = (const float*)d_in[11];
  const float* al3 = (const float*)d_in[12];
  const float* ar3 = (const float*)d_in[13];
  const float* b3 = (const float*)d_in[14];
  float* out = (float*)d_out;

  unsigned short* hb = (unsigned short*)d_ws;            // 50000*256 bf16
  float* f = (float*)(hb + (size_t)N_NODES * 256);       // 50000*256 f
  float* el = f + (size_t)N_NODES * 256;                 // 50000*4
  float* er = el + (size_t)N_NODES * 4;                  // 50000*4
  int* rowptr = (int*)(er + (size_t)N_NODES * 4);        // 50001
  int* deg = rowptr + (N_NODES + 1);                     // 50000 (cursor too)
  int* src_sorted = deg + N_NODES;                       // 800000

  const int N = N_NODES, E = N_EDGES;
  const int GX = (N + 127) / 128;

  // ---- CSR build (dst-sorted src ids) ----
  hipMemsetAsync(deg, 0, (size_t)N * sizeof(int), stream);
  hipLaunchKernelGGL(count_deg_k, dim3((E + 255) / 256), dim3(256), 0, stream,
                     dst, deg, E);
  hipLaunchKernelGGL(exscan_k, dim3(1), dim3(1024), 0, stream, deg, rowptr, N);
  hipMemcpyAsync(deg, rowptr, (size_t)N * sizeof(int),
                 hipMemcpyDeviceToDevice, stream);
  hipLaunchKernelGGL(scatter_k, dim3((E + 255) / 256), dim3(256), 0, stream,
                     src, dst, deg, src_sorted, E);

  // ---- Layer 1: feat[N,128] -> f[N,256], relu ----
  hipLaunchKernelGGL(gemm_mfma_k, dim3(GX, 4), dim3(256), 0, stream, feat, W1,
                     hb, N, 128, 256);
  hipLaunchKernelGGL((elr_kernel<4, 64>), dim3((N + 3) / 4), dim3(256), 0,
                     stream, hb, al1, ar1, el, er, N);
  hipLaunchKernelGGL((node_agg4_k<1>), dim3((N + 3) / 4), dim3(256), 0, stream,
                     hb, el, er, rowptr, src_sorted, b1, f, N);

  // ---- Layer 2: f[N,256] -> f[N,256], relu ----
  hipLaunchKernelGGL(gemm_mfma_k, dim3(GX, 4), dim3(256), 0, stream, f, W2, hb,
                     N, 256, 256);
  hipLaunchKernelGGL((elr_kernel<4, 64>), dim3((N + 3) / 4), dim3(256), 0,
                     stream, hb, al2, ar2, el, er, N);
  hipLaunchKernelGGL((node_agg4_k<1>), dim3((N + 3) / 4), dim3(256), 0, stream,
                     hb, el, er, rowptr, src_sorted, b2, f, N);

  // ---- Layer 3: f[N,256] -> out[N,64] ----
  hipLaunchKernelGGL(gemm_mfma_k, dim3(GX, 1), dim3(256), 0, stream, f, W3, hb,
                     N, 256, 64);
  hipLaunchKernelGGL((elr_kernel<1, 64>), dim3((N + 3) / 4), dim3(256), 0,
                     stream, hb, al3, ar3, el, er, N);
  hipLaunchKernelGGL(node_agg1_k, dim3((N + 3) / 4), dim3(256), 0, stream, hb,
                     el, er, rowptr, src_sorted, b3, out, N);
}

// Round 4
// 506.992 us; speedup vs baseline: 13.0777x; 1.2705x over previous
//
#include <hip/hip_runtime.h>
#include <math.h>

#define N_NODES 50000
#define N_EDGES 800000

typedef short bf8 __attribute__((ext_vector_type(8)));   // 8 bf16 (A/B frag)
typedef float f4x __attribute__((ext_vector_type(4)));   // C/D frag

__device__ __forceinline__ unsigned short f2bf(float x) {
  unsigned u = __float_as_uint(x);
  unsigned r = (u + 0x7fff + ((u >> 16) & 1)) >> 16;  // RNE
  return (unsigned short)r;
}
__device__ __forceinline__ float bf2f(unsigned short b) {
  return __uint_as_float(((unsigned)b) << 16);
}
__device__ __forceinline__ unsigned pack2(float lo, float hi) {
  return (unsigned)f2bf(lo) | ((unsigned)f2bf(hi) << 16);
}

// ---------------------------------------------------------------------------
// MFMA GEMM: Yb_bf16[N,M] = bf16(X[N,K] fp32) @ bf16(W[K,M] fp32).
// BM=128, BN=64, BK=32; 256 threads = 4 waves; per wave 2x4 tiles of 16x16.
// ---------------------------------------------------------------------------
__global__ __launch_bounds__(256) void gemm_mfma_k(
    const float* __restrict__ X, const float* __restrict__ W,
    unsigned short* __restrict__ Yb, int N, int K, int M) {
  __shared__ unsigned short As[128][40];  // [m][k], +8 pad
  __shared__ unsigned short Bs[64][40];   // [n][k], +8 pad
  const int tile_n = blockIdx.x * 128;
  const int cb = blockIdx.y * 64;
  const int t = threadIdx.x;
  const int wave = t >> 6, lane = t & 63;
  const int quad = lane >> 4, l16 = lane & 15;

  f4x acc[2][4];
#pragma unroll
  for (int i = 0; i < 2; ++i)
#pragma unroll
    for (int j = 0; j < 4; ++j) acc[i][j] = (f4x){0.f, 0.f, 0.f, 0.f};

  const int ar = t >> 1;
  const int ac0 = (t & 1) * 16;
  const int bn = t & 63;
  const int bkq = t >> 6;

  for (int k0 = 0; k0 < K; k0 += 32) {
    {
      int gr = tile_n + ar;
      uint4 u0, u1;
      if (gr < N) {
        const float* s = X + (size_t)gr * K + k0 + ac0;
        float4 a = *(const float4*)(s + 0);
        float4 b = *(const float4*)(s + 4);
        float4 c = *(const float4*)(s + 8);
        float4 d = *(const float4*)(s + 12);
        u0 = make_uint4(pack2(a.x, a.y), pack2(a.z, a.w),
                        pack2(b.x, b.y), pack2(b.z, b.w));
        u1 = make_uint4(pack2(c.x, c.y), pack2(c.z, c.w),
                        pack2(d.x, d.y), pack2(d.z, d.w));
      } else {
        u0 = make_uint4(0, 0, 0, 0);
        u1 = make_uint4(0, 0, 0, 0);
      }
      *(uint4*)&As[ar][ac0] = u0;
      *(uint4*)&As[ar][ac0 + 8] = u1;
    }
    {
      const float* s = W + (size_t)(k0 + bkq * 8) * M + cb + bn;
      float w0 = s[0 * M], w1 = s[1 * M], w2 = s[2 * M], w3 = s[3 * M];
      float w4 = s[4 * M], w5 = s[5 * M], w6 = s[6 * M], w7 = s[7 * M];
      uint4 u = make_uint4(pack2(w0, w1), pack2(w2, w3), pack2(w4, w5),
                           pack2(w6, w7));
      *(uint4*)&Bs[bn][bkq * 8] = u;
    }
    __syncthreads();
    bf8 afrag[2], bfrag[4];
#pragma unroll
    for (int rt = 0; rt < 2; ++rt)
      afrag[rt] = *(const bf8*)&As[wave * 32 + rt * 16 + l16][quad * 8];
#pragma unroll
    for (int ct = 0; ct < 4; ++ct)
      bfrag[ct] = *(const bf8*)&Bs[ct * 16 + l16][quad * 8];
#pragma unroll
    for (int rt = 0; rt < 2; ++rt)
#pragma unroll
      for (int ct = 0; ct < 4; ++ct)
        acc[rt][ct] = __builtin_amdgcn_mfma_f32_16x16x32_bf16(
            afrag[rt], bfrag[ct], acc[rt][ct], 0, 0, 0);
    __syncthreads();
  }
#pragma unroll
  for (int rt = 0; rt < 2; ++rt) {
#pragma unroll
    for (int r = 0; r < 4; ++r) {
      int row = tile_n + wave * 32 + rt * 16 + quad * 4 + r;
      if (row < N) {
#pragma unroll
        for (int ct = 0; ct < 4; ++ct)
          Yb[(size_t)row * M + cb + ct * 16 + l16] = f2bf(acc[rt][ct][r]);
      }
    }
  }
}

// ---------------------------------------------------------------------------
// el[n,h] = sum_f h[n,h,f]*al[h,f];  er likewise. One wave per node. bf16 h.
// ---------------------------------------------------------------------------
template <int H, int F>
__global__ __launch_bounds__(256) void elr_kernel(
    const unsigned short* __restrict__ hb, const float* __restrict__ al,
    const float* __restrict__ ar, float* __restrict__ el,
    float* __restrict__ er, int N) {
  int node = blockIdx.x * 4 + (threadIdx.x >> 6);
  int lane = threadIdx.x & 63;
  if (node >= N) return;
  constexpr int V = (H * F) / 64;
  constexpr int G = F / V;
  int base = lane * V;
  int head = base / F;
  int fo = base % F;
  float sl = 0.f, sr = 0.f;
  if (V == 4) {
    ushort4 hv = *(const ushort4*)(hb + (size_t)node * H * F + base);
    float x0 = bf2f(hv.x), x1 = bf2f(hv.y), x2 = bf2f(hv.z), x3 = bf2f(hv.w);
    sl = x0 * al[head * F + fo] + x1 * al[head * F + fo + 1] +
         x2 * al[head * F + fo + 2] + x3 * al[head * F + fo + 3];
    sr = x0 * ar[head * F + fo] + x1 * ar[head * F + fo + 1] +
         x2 * ar[head * F + fo + 2] + x3 * ar[head * F + fo + 3];
  } else {
    float x = bf2f(hb[(size_t)node * H * F + base]);
    sl = x * al[head * F + fo];
    sr = x * ar[head * F + fo];
  }
#pragma unroll
  for (int off = G / 2; off > 0; off >>= 1) {
    sl += __shfl_xor(sl, off, G);
    sr += __shfl_xor(sr, off, G);
  }
  if ((lane % G) == 0) {
    el[node * H + head] = sl;
    er[node * H + head] = sr;
  }
}

// ---------------------------------------------------------------------------
// CSR build: degree histogram -> per-row segment alloc (wave scan + bump)
// -> scatter. Rows land in arbitrary segment order (softmax is order-free).
// ---------------------------------------------------------------------------
__global__ __launch_bounds__(256) void count_deg_k(
    const int* __restrict__ dst, int* __restrict__ deg, int E) {
  int e = blockIdx.x * blockDim.x + threadIdx.x;
  if (e < E) atomicAdd(&deg[dst[e]], 1);
}

__global__ __launch_bounds__(256) void alloc_rows_k(
    const int* __restrict__ deg, int* __restrict__ rowstart,
    int* __restrict__ cursor, int* __restrict__ gcounter, int N) {
  int i = blockIdx.x * blockDim.x + threadIdx.x;
  int lane = threadIdx.x & 63;
  int d = (i < N) ? deg[i] : 0;
  int x = d;  // wave inclusive scan
#pragma unroll
  for (int off = 1; off < 64; off <<= 1) {
    int t = __shfl_up(x, off);
    if (lane >= off) x += t;
  }
  int wsum = __shfl(x, 63);
  int base = 0;
  if (lane == 63) base = atomicAdd(gcounter, wsum);
  base = __shfl(base, 63);
  if (i < N) {
    int mystart = base + x - d;
    rowstart[i] = mystart;
    cursor[i] = mystart;
  }
}

__global__ __launch_bounds__(256) void scatter_k(
    const int* __restrict__ src, const int* __restrict__ dst,
    int* __restrict__ cursor, int* __restrict__ src_sorted, int E) {
  int e = blockIdx.x * blockDim.x + threadIdx.x;
  if (e < E) {
    int p = atomicAdd(&cursor[dst[e]], 1);
    src_sorted[p] = src[e];
  }
}

// ---------------------------------------------------------------------------
// Per-dst fused softmax + aggregation, H=4, F=64, bf16 h. One wave per node.
// Pass 1 (lane = slot*4+head): m, then ex=exp(v-m) -> albuf (coalesced) + sum.
// Pass 2 (lane = float4 feature chunk, head=lane>>4): 4-way unrolled gather,
// normalize once at the end (acc * inv_s), + bias (+relu), one 16B store.
// ---------------------------------------------------------------------------
template <int RELU>
__global__ __launch_bounds__(256) void node_agg4_k(
    const unsigned short* __restrict__ hb, const float* __restrict__ el,
    const float* __restrict__ er, const int* __restrict__ rowstart,
    const int* __restrict__ rowend, const int* __restrict__ src_sorted,
    float* __restrict__ albuf, const float* __restrict__ bias,
    float* __restrict__ out, int N) {
  int node = blockIdx.x * 4 + (threadIdx.x >> 6);
  int lane = threadIdx.x & 63;
  if (node >= N) {  // keep barrier counts matched
    __syncthreads();
    return;
  }
  int start = rowstart[node], end = rowend[node];
  int head1 = lane & 3;
  int slot = lane >> 2;
  float er_v = er[node * 4 + head1];
  float m = -1e30f;
  for (int p = start + slot; p < end; p += 16) {
    int s = src_sorted[p];
    float v = el[s * 4 + head1] + er_v;
    v = (v >= 0.f) ? v : 0.2f * v;
    m = fmaxf(m, v);
  }
#pragma unroll
  for (int off = 4; off < 64; off <<= 1) m = fmaxf(m, __shfl_xor(m, off));
  float ssum = 0.f;
  for (int p = start + slot; p < end; p += 16) {
    int s = src_sorted[p];
    float v = el[s * 4 + head1] + er_v;
    v = (v >= 0.f) ? v : 0.2f * v;
    float ex = __expf(v - m);
    ssum += ex;
    albuf[p * 4 + head1] = ex;  // addr = start*4 + lane (+64t): coalesced
  }
#pragma unroll
  for (int off = 4; off < 64; off <<= 1) ssum += __shfl_xor(ssum, off);
  float inv_s = (end > start) ? 1.f / ssum : 0.f;
  int hf = lane >> 4;
  float inv_f = __shfl(inv_s, hf);
  __syncthreads();  // drains vmcnt: own-wave albuf stores visible to reloads
  float4 acc = make_float4(0.f, 0.f, 0.f, 0.f);
  int fo = lane << 2;
  for (int p = start; p < end; p += 4) {
    bool b1 = p + 1 < end, b2 = p + 2 < end, b3 = p + 3 < end;
    int s0 = src_sorted[p];
    int s1 = b1 ? src_sorted[p + 1] : s0;
    int s2 = b2 ? src_sorted[p + 2] : s0;
    int s3 = b3 ? src_sorted[p + 3] : s0;
    float a0 = albuf[p * 4 + hf];
    float a1 = b1 ? albuf[(p + 1) * 4 + hf] : 0.f;
    float a2 = b2 ? albuf[(p + 2) * 4 + hf] : 0.f;
    float a3 = b3 ? albuf[(p + 3) * 4 + hf] : 0.f;
    ushort4 h0 = *(const ushort4*)(hb + (size_t)s0 * 256 + fo);
    ushort4 h1 = *(const ushort4*)(hb + (size_t)s1 * 256 + fo);
    ushort4 h2 = *(const ushort4*)(hb + (size_t)s2 * 256 + fo);
    ushort4 h3 = *(const ushort4*)(hb + (size_t)s3 * 256 + fo);
    acc.x += bf2f(h0.x) * a0 + bf2f(h1.x) * a1 + bf2f(h2.x) * a2 + bf2f(h3.x) * a3;
    acc.y += bf2f(h0.y) * a0 + bf2f(h1.y) * a1 + bf2f(h2.y) * a2 + bf2f(h3.y) * a3;
    acc.z += bf2f(h0.z) * a0 + bf2f(h1.z) * a1 + bf2f(h2.z) * a2 + bf2f(h3.z) * a3;
    acc.w += bf2f(h0.w) * a0 + bf2f(h1.w) * a1 + bf2f(h2.w) * a2 + bf2f(h3.w) * a3;
  }
  const float4 b = *(const float4*)(bias + fo);
  acc.x = acc.x * inv_f + b.x;
  acc.y = acc.y * inv_f + b.y;
  acc.z = acc.z * inv_f + b.z;
  acc.w = acc.w * inv_f + b.w;
  if (RELU) {
    acc.x = fmaxf(acc.x, 0.f); acc.y = fmaxf(acc.y, 0.f);
    acc.z = fmaxf(acc.z, 0.f); acc.w = fmaxf(acc.w, 0.f);
  }
  *(float4*)(out + (size_t)node * 256 + fo) = acc;
}

// H=1, F=64 variant: lane = slot in pass 1, lane = feature in pass 2.
__global__ __launch_bounds__(256) void node_agg1_k(
    const unsigned short* __restrict__ hb, const float* __restrict__ el,
    const float* __restrict__ er, const int* __restrict__ rowstart,
    const int* __restrict__ rowend, const int* __restrict__ src_sorted,
    float* __restrict__ albuf, const float* __restrict__ bias,
    float* __restrict__ out, int N) {
  int node = blockIdx.x * 4 + (threadIdx.x >> 6);
  int lane = threadIdx.x & 63;
  if (node >= N) {
    __syncthreads();
    return;
  }
  int start = rowstart[node], end = rowend[node];
  float er_v = er[node];
  float m = -1e30f;
  for (int p = start + lane; p < end; p += 64) {
    float v = el[src_sorted[p]] + er_v;
    v = (v >= 0.f) ? v : 0.2f * v;
    m = fmaxf(m, v);
  }
#pragma unroll
  for (int off = 1; off < 64; off <<= 1) m = fmaxf(m, __shfl_xor(m, off));
  float ssum = 0.f;
  for (int p = start + lane; p < end; p += 64) {
    float v = el[src_sorted[p]] + er_v;
    v = (v >= 0.f) ? v : 0.2f * v;
    float ex = __expf(v - m);
    ssum += ex;
    albuf[p] = ex;
  }
#pragma unroll
  for (int off = 1; off < 64; off <<= 1) ssum += __shfl_xor(ssum, off);
  float inv_s = (end > start) ? 1.f / ssum : 0.f;
  __syncthreads();
  float acc = 0.f;
  for (int p = start; p < end; p += 4) {
    bool b1 = p + 1 < end, b2 = p + 2 < end, b3 = p + 3 < end;
    int s0 = src_sorted[p];
    int s1 = b1 ? src_sorted[p + 1] : s0;
    int s2 = b2 ? src_sorted[p + 2] : s0;
    int s3 = b3 ? src_sorted[p + 3] : s0;
    float a0 = albuf[p];
    float a1 = b1 ? albuf[p + 1] : 0.f;
    float a2 = b2 ? albuf[p + 2] : 0.f;
    float a3 = b3 ? albuf[p + 3] : 0.f;
    float h0 = bf2f(hb[(size_t)s0 * 64 + lane]);
    float h1 = bf2f(hb[(size_t)s1 * 64 + lane]);
    float h2 = bf2f(hb[(size_t)s2 * 64 + lane]);
    float h3 = bf2f(hb[(size_t)s3 * 64 + lane]);
    acc += h0 * a0 + h1 * a1 + h2 * a2 + h3 * a3;
  }
  out[(size_t)node * 64 + lane] = acc * inv_s + bias[lane];
}

// ---------------------------------------------------------------------------
extern "C" void kernel_launch(void* const* d_in, const int* in_sizes, int n_in,
                              void* d_out, int out_size, void* d_ws,
                              size_t ws_size, hipStream_t stream) {
  const float* feat = (const float*)d_in[0];
  const int* src = (const int*)d_in[1];
  const int* dst = (const int*)d_in[2];
  const float* W1 = (const float*)d_in[3];
  const float* al1 = (const float*)d_in[4];
  const float* ar1 = (const float*)d_in[5];
  const float* b1 = (const float*)d_in[6];
  const float* W2 = (const float*)d_in[7];
  const float* al2 = (const float*)d_in[8];
  const float* ar2 = (const float*)d_in[9];
  const float* b2 = (const float*)d_in[10];
  const float* W3 = (const float*)d_in[11];
  const float* al3 = (const float*)d_in[12];
  const float* ar3 = (const float*)d_in[13];
  const float* b3 = (const float*)d_in[14];
  float* out = (float*)d_out;

  unsigned short* hb = (unsigned short*)d_ws;          // N*256 bf16
  float* f = (float*)(hb + (size_t)N_NODES * 256);     // N*256 f32
  float* el = f + (size_t)N_NODES * 256;               // N*4
  float* er = el + (size_t)N_NODES * 4;                // N*4
  int* rowstart = (int*)(er + (size_t)N_NODES * 4);    // N
  int* cursor = rowstart + N_NODES;                    // N
  int* deg = cursor + N_NODES;                         // N (+1 gcounter)
  int* gcounter = deg + N_NODES;                       // 1
  int* src_sorted = gcounter + 1;                      // E
  float* albuf = (float*)(src_sorted + N_EDGES);       // E*4

  const int N = N_NODES, E = N_EDGES;
  const int GX = (N + 127) / 128;

  // ---- CSR build ----
  hipMemsetAsync(deg, 0, (size_t)(N + 1) * sizeof(int), stream);  // deg+gcnt
  hipLaunchKernelGGL(count_deg_k, dim3((E + 255) / 256), dim3(256), 0, stream,
                     dst, deg, E);
  hipLaunchKernelGGL(alloc_rows_k, dim3((N + 255) / 256), dim3(256), 0, stream,
                     deg, rowstart, cursor, gcounter, N);
  hipLaunchKernelGGL(scatter_k, dim3((E + 255) / 256), dim3(256), 0, stream,
                     src, dst, cursor, src_sorted, E);
  // after scatter, cursor[i] == rowstart[i] + deg[i] == row end

  // ---- Layer 1: feat[N,128] -> f[N,256], relu ----
  hipLaunchKernelGGL(gemm_mfma_k, dim3(GX, 4), dim3(256), 0, stream, feat, W1,
                     hb, N, 128, 256);
  hipLaunchKernelGGL((elr_kernel<4, 64>), dim3((N + 3) / 4), dim3(256), 0,
                     stream, hb, al1, ar1, el, er, N);
  hipLaunchKernelGGL((node_agg4_k<1>), dim3((N + 3) / 4), dim3(256), 0, stream,
                     hb, el, er, rowstart, cursor, src_sorted, albuf, b1, f, N);

  // ---- Layer 2: f[N,256] -> f[N,256], relu ----
  hipLaunchKernelGGL(gemm_mfma_k, dim3(GX, 4), dim3(256), 0, stream, f, W2, hb,
                     N, 256, 256);
  hipLaunchKernelGGL((elr_kernel<4, 64>), dim3((N + 3) / 4), dim3(256), 0,
                     stream, hb, al2, ar2, el, er, N);
  hipLaunchKernelGGL((node_agg4_k<1>), dim3((N + 3) / 4), dim3(256), 0, stream,
                     hb, el, er, rowstart, cursor, src_sorted, albuf, b2, f, N);

  // ---- Layer 3: f[N,256] -> out[N,64] ----
  hipLaunchKernelGGL(gemm_mfma_k, dim3(GX, 1), dim3(256), 0, stream, f, W3, hb,
                     N, 256, 64);
  hipLaunchKernelGGL((elr_kernel<1, 64>), dim3((N + 3) / 4), dim3(256), 0,
                     stream, hb, al3, ar3, el, er, N);
  hipLaunchKernelGGL(node_agg1_k, dim3((N + 3) / 4), dim3(256), 0, stream, hb,
                     el, er, rowstart, cursor, src_sorted, albuf, b3, out, N);
}

// Round 5
// 425.184 us; speedup vs baseline: 15.5940x; 1.1924x over previous
//
#include <hip/hip_runtime.h>
#include <math.h>

#define N_NODES 50000
#define N_EDGES 800000

typedef short bf8 __attribute__((ext_vector_type(8)));    // 8 bf16 (A/B frag)
typedef float f4x __attribute__((ext_vector_type(4)));    // C/D frag
typedef unsigned short us8 __attribute__((ext_vector_type(8)));  // 16B bf16

__device__ __forceinline__ unsigned short f2bf(float x) {
  unsigned u = __float_as_uint(x);
  unsigned r = (u + 0x7fff + ((u >> 16) & 1)) >> 16;  // RNE
  return (unsigned short)r;
}
__device__ __forceinline__ float bf2f(unsigned short b) {
  return __uint_as_float(((unsigned)b) << 16);
}
__device__ __forceinline__ unsigned pack2(float lo, float hi) {
  return (unsigned)f2bf(lo) | ((unsigned)f2bf(hi) << 16);
}

// ---------------------------------------------------------------------------
// MFMA GEMM + fused el/er epilogue.
// Yb[N,M](bf16) = A[N,K] @ W[K,M](fp32->bf16);  el/er[n,head] = h.al/h.ar
// BM=128, BN=64 (= one head), BK=32; 256 thr = 4 waves; 2x4 16x16 tiles/wave.
// ABF16: A source is bf16 (fb) vs fp32 (feat).
// ---------------------------------------------------------------------------
template <int ABF16>
__global__ __launch_bounds__(256) void gemm_mfma_k(
    const void* __restrict__ Xv, const float* __restrict__ W,
    unsigned short* __restrict__ Yb, float* __restrict__ el,
    float* __restrict__ er, const float* __restrict__ al,
    const float* __restrict__ ar, int N, int K, int M) {
  __shared__ unsigned short As[128][40];  // [m][k], +8 pad
  __shared__ unsigned short Bs[64][40];   // [n][k], +8 pad
  const int tile_n = blockIdx.x * 128;
  const int cb = blockIdx.y * 64;  // == head*64
  const int t = threadIdx.x;
  const int wave = t >> 6, lane = t & 63;
  const int quad = lane >> 4, l16 = lane & 15;

  f4x acc[2][4];
#pragma unroll
  for (int i = 0; i < 2; ++i)
#pragma unroll
    for (int j = 0; j < 4; ++j) acc[i][j] = (f4x){0.f, 0.f, 0.f, 0.f};

  const int ar_ = t >> 1;          // A stage row (0..127)
  const int ac0 = (t & 1) * 16;    // A stage k base
  const int bn = t & 63;           // B stage col
  const int bkq = t >> 6;          // B stage k-quad

  for (int k0 = 0; k0 < K; k0 += 32) {
    if (ABF16) {
      const unsigned short* Xb = (const unsigned short*)Xv;
      int gr = tile_n + ar_;
      us8 u0 = (us8)0, u1 = (us8)0;
      if (gr < N) {
        const unsigned short* s = Xb + (size_t)gr * K + k0 + ac0;
        u0 = *(const us8*)(s + 0);
        u1 = *(const us8*)(s + 8);
      }
      *(us8*)&As[ar_][ac0] = u0;
      *(us8*)&As[ar_][ac0 + 8] = u1;
    } else {
      const float* X = (const float*)Xv;
      int gr = tile_n + ar_;
      uint4 u0, u1;
      if (gr < N) {
        const float* s = X + (size_t)gr * K + k0 + ac0;
        float4 a = *(const float4*)(s + 0);
        float4 b = *(const float4*)(s + 4);
        float4 c = *(const float4*)(s + 8);
        float4 d = *(const float4*)(s + 12);
        u0 = make_uint4(pack2(a.x, a.y), pack2(a.z, a.w),
                        pack2(b.x, b.y), pack2(b.z, b.w));
        u1 = make_uint4(pack2(c.x, c.y), pack2(c.z, c.w),
                        pack2(d.x, d.y), pack2(d.z, d.w));
      } else {
        u0 = make_uint4(0, 0, 0, 0);
        u1 = make_uint4(0, 0, 0, 0);
      }
      *(uint4*)&As[ar_][ac0] = u0;
      *(uint4*)&As[ar_][ac0 + 8] = u1;
    }
    {
      const float* s = W + (size_t)(k0 + bkq * 8) * M + cb + bn;
      float w0 = s[0 * M], w1 = s[1 * M], w2 = s[2 * M], w3 = s[3 * M];
      float w4 = s[4 * M], w5 = s[5 * M], w6 = s[6 * M], w7 = s[7 * M];
      uint4 u = make_uint4(pack2(w0, w1), pack2(w2, w3), pack2(w4, w5),
                           pack2(w6, w7));
      *(uint4*)&Bs[bn][bkq * 8] = u;
    }
    __syncthreads();
    bf8 afrag[2], bfrag[4];
#pragma unroll
    for (int rt = 0; rt < 2; ++rt)
      afrag[rt] = *(const bf8*)&As[wave * 32 + rt * 16 + l16][quad * 8];
#pragma unroll
    for (int ct = 0; ct < 4; ++ct)
      bfrag[ct] = *(const bf8*)&Bs[ct * 16 + l16][quad * 8];
#pragma unroll
    for (int rt = 0; rt < 2; ++rt)
#pragma unroll
      for (int ct = 0; ct < 4; ++ct)
        acc[rt][ct] = __builtin_amdgcn_mfma_f32_16x16x32_bf16(
            afrag[rt], bfrag[ct], acc[rt][ct], 0, 0, 0);
    __syncthreads();
  }
  // --- epilogue: store bf16 h + fused el/er (this block = one full head) ---
  const int H = M >> 6;
  const int head = cb >> 6;
  float al4[4], ar4[4];
#pragma unroll
  for (int ct = 0; ct < 4; ++ct) {
    al4[ct] = al[cb + ct * 16 + l16];
    ar4[ct] = ar[cb + ct * 16 + l16];
  }
#pragma unroll
  for (int rt = 0; rt < 2; ++rt) {
#pragma unroll
    for (int r = 0; r < 4; ++r) {
      int row = tile_n + wave * 32 + rt * 16 + quad * 4 + r;
      float pl = 0.f, pr = 0.f;
#pragma unroll
      for (int ct = 0; ct < 4; ++ct) {
        float y = acc[rt][ct][r];
        pl += y * al4[ct];
        pr += y * ar4[ct];
        if (row < N) Yb[(size_t)row * M + cb + ct * 16 + l16] = f2bf(y);
      }
#pragma unroll
      for (int off = 1; off < 16; off <<= 1) {
        pl += __shfl_xor(pl, off);
        pr += __shfl_xor(pr, off);
      }
      if (l16 == 0 && row < N) {
        el[row * H + head] = pl;
        er[row * H + head] = pr;
      }
    }
  }
}

// ---------------------------------------------------------------------------
// CSR build: degree histogram -> per-row segment alloc (wave scan + bump)
// -> scatter. Rows land in arbitrary segment order (softmax is order-free).
// ---------------------------------------------------------------------------
__global__ __launch_bounds__(256) void count_deg_k(
    const int* __restrict__ dst, int* __restrict__ deg, int E) {
  int e = blockIdx.x * blockDim.x + threadIdx.x;
  if (e < E) atomicAdd(&deg[dst[e]], 1);
}

__global__ __launch_bounds__(256) void alloc_rows_k(
    const int* __restrict__ deg, int* __restrict__ rowstart,
    int* __restrict__ cursor, int* __restrict__ gcounter, int N) {
  int i = blockIdx.x * blockDim.x + threadIdx.x;
  int lane = threadIdx.x & 63;
  int d = (i < N) ? deg[i] : 0;
  int x = d;
#pragma unroll
  for (int off = 1; off < 64; off <<= 1) {
    int t = __shfl_up(x, off);
    if (lane >= off) x += t;
  }
  int wsum = __shfl(x, 63);
  int base = 0;
  if (lane == 63) base = atomicAdd(gcounter, wsum);
  base = __shfl(base, 63);
  if (i < N) {
    int mystart = base + x - d;
    rowstart[i] = mystart;
    cursor[i] = mystart;
  }
}

__global__ __launch_bounds__(256) void scatter_k(
    const int* __restrict__ src, const int* __restrict__ dst,
    int* __restrict__ cursor, int* __restrict__ src_sorted, int E) {
  int e = blockIdx.x * blockDim.x + threadIdx.x;
  if (e < E) {
    int p = atomicAdd(&cursor[dst[e]], 1);
    src_sorted[p] = src[e];
  }
}

// ---------------------------------------------------------------------------
// Fused softmax + aggregation, H=4, F=64, bf16 h. One wave per dst node.
// Pass 1 (lane = slot*4+head): ex=exp(leakyrelu(el+er)) -> albuf + head sums.
// Pass 2: half-wave per edge (32 lanes x ushort8 = 512B row), 2 edges/iter,
// unroll x4 -> 8 edges in flight; shfl_xor(32) combine; bf16 store + bias/relu.
// ---------------------------------------------------------------------------
template <int RELU>
__global__ __launch_bounds__(256) void node_agg4_k(
    const unsigned short* __restrict__ hb, const float* __restrict__ el,
    const float* __restrict__ er, const int* __restrict__ rowstart,
    const int* __restrict__ rowend, const int* __restrict__ src_sorted,
    float* __restrict__ albuf, const float* __restrict__ bias,
    unsigned short* __restrict__ outb, int N) {
  int node = blockIdx.x * 4 + (threadIdx.x >> 6);
  int lane = threadIdx.x & 63;
  if (node >= N) {
    __syncthreads();
    return;
  }
  int start = rowstart[node], end = rowend[node];
  int head1 = lane & 3;
  int slot = lane >> 2;
  float er_v = er[node * 4 + head1];
  float ssum = 0.f;
  for (int p = start + slot; p < end; p += 16) {
    int s = src_sorted[p];
    float v = el[s * 4 + head1] + er_v;
    v = (v >= 0.f) ? v : 0.2f * v;
    float ex = __expf(v);
    ssum += ex;
    albuf[p * 4 + head1] = ex;  // coalesced
  }
#pragma unroll
  for (int off = 4; off < 64; off <<= 1) ssum += __shfl_xor(ssum, off);
  float inv_s = (end > start) ? 1.f / ssum : 0.f;
  int eslot = lane >> 5;       // 0/1: which edge of the pair
  int flane = lane & 31;       // feature chunk
  int fo8 = flane << 3;        // 8 feats = 16B
  int headf = fo8 >> 6;
  float inv_f = __shfl(inv_s, headf);
  __syncthreads();  // drain own-wave albuf stores before reload
  float acc[8] = {0.f, 0.f, 0.f, 0.f, 0.f, 0.f, 0.f, 0.f};
  for (int p0 = start; p0 < end; p0 += 8) {
    int sj[4];
    float aj[4];
#pragma unroll
    for (int j = 0; j < 4; ++j) {
      int p = p0 + 2 * j + eslot;
      bool v = p < end;
      sj[j] = 0;
      aj[j] = 0.f;
      if (v) {
        sj[j] = src_sorted[p];
        aj[j] = albuf[p * 4 + headf];
      }
    }
#pragma unroll
    for (int j = 0; j < 4; ++j) {
      us8 hv = *(const us8*)(hb + (size_t)sj[j] * 256 + fo8);
#pragma unroll
      for (int q = 0; q < 8; ++q) acc[q] += bf2f(hv[q]) * aj[j];
    }
  }
#pragma unroll
  for (int q = 0; q < 8; ++q) acc[q] += __shfl_xor(acc[q], 32);
  if (eslot == 0) {
    us8 o;
#pragma unroll
    for (int q = 0; q < 8; ++q) {
      float v = acc[q] * inv_f + bias[fo8 + q];
      if (RELU) v = fmaxf(v, 0.f);
      o[q] = f2bf(v);
    }
    *(us8*)(outb + (size_t)node * 256 + fo8) = o;
  }
}

// H=1, F=64: 8 lanes x ushort8 = 128B row; 8 edges/iter, unroll x2 -> 16 in
// flight. fp32 output (final layer).
__global__ __launch_bounds__(256) void node_agg1_k(
    const unsigned short* __restrict__ hb, const float* __restrict__ el,
    const float* __restrict__ er, const int* __restrict__ rowstart,
    const int* __restrict__ rowend, const int* __restrict__ src_sorted,
    float* __restrict__ albuf, const float* __restrict__ bias,
    float* __restrict__ out, int N) {
  int node = blockIdx.x * 4 + (threadIdx.x >> 6);
  int lane = threadIdx.x & 63;
  if (node >= N) {
    __syncthreads();
    return;
  }
  int start = rowstart[node], end = rowend[node];
  float er_v = er[node];
  float ssum = 0.f;
  for (int p = start + lane; p < end; p += 64) {
    float v = el[src_sorted[p]] + er_v;
    v = (v >= 0.f) ? v : 0.2f * v;
    float ex = __expf(v);
    ssum += ex;
    albuf[p] = ex;
  }
#pragma unroll
  for (int off = 1; off < 64; off <<= 1) ssum += __shfl_xor(ssum, off);
  float inv_s = (end > start) ? 1.f / ssum : 0.f;
  int eslot = lane >> 3;   // 0..7
  int flane = lane & 7;
  int fo8 = flane << 3;
  __syncthreads();
  float acc[8] = {0.f, 0.f, 0.f, 0.f, 0.f, 0.f, 0.f, 0.f};
  for (int p0 = start; p0 < end; p0 += 16) {
    int sj[2];
    float aj[2];
#pragma unroll
    for (int j = 0; j < 2; ++j) {
      int p = p0 + 8 * j + eslot;
      bool v = p < end;
      sj[j] = 0;
      aj[j] = 0.f;
      if (v) {
        sj[j] = src_sorted[p];
        aj[j] = albuf[p];
      }
    }
#pragma unroll
    for (int j = 0; j < 2; ++j) {
      us8 hv = *(const us8*)(hb + (size_t)sj[j] * 64 + fo8);
#pragma unroll
      for (int q = 0; q < 8; ++q) acc[q] += bf2f(hv[q]) * aj[j];
    }
  }
#pragma unroll
  for (int off = 8; off < 64; off <<= 1)
#pragma unroll
    for (int q = 0; q < 8; ++q) acc[q] += __shfl_xor(acc[q], off);
  if (eslot == 0) {
    float* o = out + (size_t)node * 64 + fo8;
#pragma unroll
    for (int q = 0; q < 8; ++q) o[q] = acc[q] * inv_s + bias[fo8 + q];
  }
}

// ---------------------------------------------------------------------------
extern "C" void kernel_launch(void* const* d_in, const int* in_sizes, int n_in,
                              void* d_out, int out_size, void* d_ws,
                              size_t ws_size, hipStream_t stream) {
  const float* feat = (const float*)d_in[0];
  const int* src = (const int*)d_in[1];
  const int* dst = (const int*)d_in[2];
  const float* W1 = (const float*)d_in[3];
  const float* al1 = (const float*)d_in[4];
  const float* ar1 = (const float*)d_in[5];
  const float* b1 = (const float*)d_in[6];
  const float* W2 = (const float*)d_in[7];
  const float* al2 = (const float*)d_in[8];
  const float* ar2 = (const float*)d_in[9];
  const float* b2 = (const float*)d_in[10];
  const float* W3 = (const float*)d_in[11];
  const float* al3 = (const float*)d_in[12];
  const float* ar3 = (const float*)d_in[13];
  const float* b3 = (const float*)d_in[14];
  float* out = (float*)d_out;

  unsigned short* hb = (unsigned short*)d_ws;             // N*256 bf16
  unsigned short* fb = hb + (size_t)N_NODES * 256;        // N*256 bf16
  float* el = (float*)(fb + (size_t)N_NODES * 256);       // N*4
  float* er = el + (size_t)N_NODES * 4;                   // N*4
  int* rowstart = (int*)(er + (size_t)N_NODES * 4);       // N
  int* cursor = rowstart + N_NODES;                       // N
  int* deg = cursor + N_NODES;                            // N
  int* gcounter = deg + N_NODES;                          // 1
  int* src_sorted = gcounter + 1;                         // E
  float* albuf = (float*)(src_sorted + N_EDGES);          // E*4

  const int N = N_NODES, E = N_EDGES;
  const int GX = (N + 127) / 128;

  // ---- CSR build ----
  hipMemsetAsync(deg, 0, (size_t)(N + 1) * sizeof(int), stream);
  hipLaunchKernelGGL(count_deg_k, dim3((E + 255) / 256), dim3(256), 0, stream,
                     dst, deg, E);
  hipLaunchKernelGGL(alloc_rows_k, dim3((N + 255) / 256), dim3(256), 0, stream,
                     deg, rowstart, cursor, gcounter, N);
  hipLaunchKernelGGL(scatter_k, dim3((E + 255) / 256), dim3(256), 0, stream,
                     src, dst, cursor, src_sorted, E);
  // after scatter, cursor[i] == row end

  // ---- Layer 1: feat[N,128] -> fb[N,256] (bf16), relu ----
  hipLaunchKernelGGL((gemm_mfma_k<0>), dim3(GX, 4), dim3(256), 0, stream, feat,
                     W1, hb, el, er, al1, ar1, N, 128, 256);
  hipLaunchKernelGGL((node_agg4_k<1>), dim3((N + 3) / 4), dim3(256), 0, stream,
                     hb, el, er, rowstart, cursor, src_sorted, albuf, b1, fb,
                     N);

  // ---- Layer 2: fb[N,256] -> fb[N,256] (bf16), relu ----
  hipLaunchKernelGGL((gemm_mfma_k<1>), dim3(GX, 4), dim3(256), 0, stream, fb,
                     W2, hb, el, er, al2, ar2, N, 256, 256);
  hipLaunchKernelGGL((node_agg4_k<1>), dim3((N + 3) / 4), dim3(256), 0, stream,
                     hb, el, er, rowstart, cursor, src_sorted, albuf, b2, fb,
                     N);

  // ---- Layer 3: fb[N,256] -> out[N,64] (fp32) ----
  hipLaunchKernelGGL((gemm_mfma_k<1>), dim3(GX, 1), dim3(256), 0, stream, fb,
                     W3, hb, el, er, al3, ar3, N, 256, 64);
  hipLaunchKernelGGL(node_agg1_k, dim3((N + 3) / 4), dim3(256), 0, stream, hb,
                     el, er, rowstart, cursor, src_sorted, albuf, b3, out, N);
}